// Round 10
// baseline (345.429 us; speedup 1.0000x reference)
//
#include <hip/hip_runtime.h>
#include <hip/hip_bf16.h>
#include <math.h>

// ---------------------------------------------------------------------------
// SpatialTransformer block. R23: depth-3 register pipeline for the BK=64
// GEMMs (gemm_bf16 + gemm_pout) — load for step s+3 issued at step s, giving
// a 2-step load-to-consume lead that covers L2/HBM latency (was 1 step).
// Rest identical to R22.
// B=8, C=320, H=W=32 (HW=1024), HEADS=8, DHEAD=40, CTX=77x768, FF_INNER=1280.
// ---------------------------------------------------------------------------

#define Bsz   8
#define Cch   320
#define HW    1024
#define NTOK  (Bsz*HW)          // 8192
#define HEADS 8
#define DHEAD 40
#define CTXL  77
#define CTXD  768
#define FFI   1280
#define MCTX  (Bsz*CTXL)        // 616
#define MCTXP 640               // padded rows for ctx GEMM

typedef unsigned short u16;
typedef unsigned long long u64;
typedef __attribute__((ext_vector_type(8))) u16    u16x8;
typedef __attribute__((ext_vector_type(4))) u16    u16x4;
typedef __attribute__((ext_vector_type(8))) __bf16 bf16x8;
typedef __attribute__((ext_vector_type(4))) float  f32x4;

__device__ inline u16 f2b(float f) {            // fp32 -> bf16 RNE
    unsigned u = __float_as_uint(f);
    return (u16)((u + 0x7FFFu + ((u >> 16) & 1u)) >> 16);
}

// ------------------------- GroupNorm pass 2: normalize + CHW->token-major
__global__ __launch_bounds__(256) void gn_apply(
    const float* __restrict__ x, const float* __restrict__ gnA,
    const float* __restrict__ gnB, u16* __restrict__ out)
{
    __shared__ u16 T[64*72];
    const int tid = threadIdx.x;
    const int c0 = blockIdx.x * 64;
    const int p0 = blockIdx.y * 64;
    const int b  = blockIdx.z;
    for (int e = tid; e < 512; e += 256) {
        int r = e >> 3, ch = e & 7;
        const float* src = x + ((size_t)(b*Cch + c0 + r))*HW + p0 + ch*8;
        float a  = gnA[b*Cch + c0 + r];
        float bb = gnB[b*Cch + c0 + r];
        float4 v0 = *(const float4*)src;
        float4 v1 = *(const float4*)(src + 4);
        u16x8 val;
        val[0] = f2b(v0.x*a + bb); val[1] = f2b(v0.y*a + bb);
        val[2] = f2b(v0.z*a + bb); val[3] = f2b(v0.w*a + bb);
        val[4] = f2b(v1.x*a + bb); val[5] = f2b(v1.y*a + bb);
        val[6] = f2b(v1.z*a + bb); val[7] = f2b(v1.w*a + bb);
        *(u16x8*)&T[r*72 + (ch ^ (r & 7))*8] = val;
    }
    __syncthreads();
    for (int e = tid; e < 4096; e += 256) {
        int p = e >> 6, c = e & 63;
        u16 v = T[c*72 + (((p >> 3) ^ (c & 7))*8) + (p & 7)];
        out[((size_t)(b*HW + p0 + p))*Cch + c0 + c] = v;
    }
}

// ------------------------------------------------------- LayerNorm -> bf16
__global__ __launch_bounds__(256) void layernorm_kernel(
    const float* __restrict__ in, const float* __restrict__ s,
    const float* __restrict__ bgain, u16* __restrict__ out)
{
    int t = blockIdx.x*4 + (threadIdx.x >> 6);
    int lane = threadIdx.x & 63;
    const float* row = in + (size_t)t*Cch;
    float v[5];
    float sum = 0.f, sq = 0.f;
    #pragma unroll
    for (int i = 0; i < 5; ++i) {
        v[i] = row[lane + 64*i];
        sum += v[i]; sq += v[i]*v[i];
    }
    #pragma unroll
    for (int off = 32; off > 0; off >>= 1) {
        sum += __shfl_xor(sum, off);
        sq  += __shfl_xor(sq,  off);
    }
    float mean = sum * (1.f/320.f);
    float var  = sq  * (1.f/320.f) - mean*mean;
    float inv  = rsqrtf(var + 1e-5f);
    u16* orow = out + (size_t)t*Cch;
    #pragma unroll
    for (int i = 0; i < 5; ++i) {
        int c = lane + 64*i;
        orow[c] = f2b((v[i]-mean)*inv*s[c] + bgain[c]);
    }
}

// ------------- fused preamble: weights + ctx + mask bits + gn statistics
struct WDesc { const float* src; u16* dst; int K; int N; int tiles; float scl; };
struct WPack { WDesc w[12]; };

#define WT_TILES 620
#define CTXBLK   240     // 640*768 / 2048

__global__ __launch_bounds__(256) void preamble(
    WPack p, const float* __restrict__ ctxsrc, u16* __restrict__ ctxdst,
    const void* __restrict__ vis, const void* __restrict__ v2t,
    u64* __restrict__ bvis, u64* __restrict__ bv2t,
    const float* __restrict__ x, const float* __restrict__ gscale,
    const float* __restrict__ gbias, float* __restrict__ gnA,
    float* __restrict__ gnB)
{
    __shared__ u16 T[64*72];
    int blk = blockIdx.x;
    int tid = threadIdx.x;
    if (blk < WT_TILES) {                      // tiled weight transpose
        int t = blk;
        #pragma unroll
        for (int i = 0; i < 12; ++i) {
            int nt = p.w[i].tiles;
            if (t < nt) {
                const int K = p.w[i].K, N = p.w[i].N;
                const int ntN = N >> 6;
                const int tk = t / ntN, tn = t - tk*ntN;
                const float scl = p.w[i].scl;
                const float* src = p.w[i].src;
                u16* dst = p.w[i].dst;
                for (int e = tid; e < 512; e += 256) {
                    int r = e >> 3, ch = e & 7;
                    const float* sp = src + (size_t)(tk*64 + r)*N + tn*64 + ch*8;
                    float4 v0 = *(const float4*)sp;
                    float4 v1 = *(const float4*)(sp + 4);
                    u16x8 val;
                    val[0] = f2b(v0.x*scl); val[1] = f2b(v0.y*scl);
                    val[2] = f2b(v0.z*scl); val[3] = f2b(v0.w*scl);
                    val[4] = f2b(v1.x*scl); val[5] = f2b(v1.y*scl);
                    val[6] = f2b(v1.z*scl); val[7] = f2b(v1.w*scl);
                    *(u16x8*)&T[r*72 + (ch ^ (r & 7))*8] = val;
                }
                __syncthreads();
                for (int e = tid; e < 4096; e += 256) {
                    int n = e >> 6, k = e & 63;
                    u16 v = T[k*72 + (((n >> 3) ^ (k & 7))*8) + (n & 7)];
                    dst[(size_t)(tn*64 + n)*K + tk*64 + k] = v;
                }
                return;
            }
            t -= nt;
        }
        return;
    }
    if (blk < WT_TILES + CTXBLK) {             // ctx fp32 -> bf16 (padded)
        int idx = (blk - WT_TILES)*2048 + tid*8;
        int r = idx / CTXD;
        u16x8 val = {};
        if (r < MCTX) {
            float4 v0 = *(const float4*)(ctxsrc + idx);
            float4 v1 = *(const float4*)(ctxsrc + idx + 4);
            val[0] = f2b(v0.x); val[1] = f2b(v0.y);
            val[2] = f2b(v0.z); val[3] = f2b(v0.w);
            val[4] = f2b(v1.x); val[5] = f2b(v1.y);
            val[6] = f2b(v1.z); val[7] = f2b(v1.w);
        }
        *(u16x8*)(ctxdst + idx) = val;
        return;
    }
    if (blk >= WT_TILES + CTXBLK + 4096) {     // groupnorm statistics role
        int gb = blk - (WT_TILES + CTXBLK + 4096);   // 0..255
        int b = gb >> 5, g = gb & 31;
        __shared__ float rs[256], rq[256];
        const float4* xg = (const float4*)(x + ((size_t)b*Cch + g*10)*HW);
        float s = 0.f, q = 0.f;
        #pragma unroll
        for (int i = 0; i < 10; ++i) {
            float4 v = xg[tid + i*256];
            s += v.x + v.y + v.z + v.w;
            q += v.x*v.x + v.y*v.y + v.z*v.z + v.w*v.w;
        }
        rs[tid] = s; rq[tid] = q; __syncthreads();
        for (int off = 128; off > 0; off >>= 1) {
            if (tid < off) { rs[tid] += rs[tid+off]; rq[tid] += rq[tid+off]; }
            __syncthreads();
        }
        if (tid < 10) {
            float mean = rs[0] * (1.f/10240.f);
            float var  = rq[0] * (1.f/10240.f) - mean*mean;
            float inv  = rsqrtf(var + 1e-6f);
            int chn = g*10 + tid;
            float a = inv * gscale[chn];
            gnA[b*Cch + chn] = a;
            gnB[b*Cch + chn] = gbias[chn] - mean*a;
        }
        return;
    }
    // mask -> bit words; dtype probed from vis[0..4096)
    __shared__ int any;
    if (tid == 0) any = 0;
    __syncthreads();
    const unsigned char* probe = (const unsigned char*)vis;
    for (int i = tid; i < 4096; i += 256)
        if ((i & 3) && probe[i]) any = 1;
    __syncthreads();
    const int isU8 = any;
    int mb = blk - WT_TILES - CTXBLK;          // 0..4095
    const void* mask; u64* bits; int Lkv, nw;
    if (mb < 2048) { mask = vis; bits = bvis; Lkv = HW;   nw = 16; }
    else           { mask = v2t; bits = bv2t; Lkv = CTXL; nw = 2; mb -= 2048; }
    const int wv = tid >> 6, lane = tid & 63;
    const int row = mb*4 + wv;
    const unsigned char* m8  = (const unsigned char*)mask;
    const int*           m32 = (const int*)mask;
    const size_t base = (size_t)row * Lkv;
    for (int w = 0; w < nw; ++w) {
        int j = w*64 + lane;
        bool on = (j < Lkv) && (isU8 ? (m8[base+j] != 0) : (m32[base+j] != 0));
        u64 word = __ballot(on);
        if (lane == 0) bits[(size_t)row*nw + w] = word;
    }
}

// --------- bf16 MFMA GEMM, BK=64, depth-3 register pipeline.
// out[M,N] = A[M,K] @ Wt[N,K]^T (+bias)(+res). Block 128x64, 512 thr / 8 waves.
// Grid (m-blocks, n-blocks): m fastest (XCD locality). K must be mult of 64.
__global__ __launch_bounds__(512) void gemm_bf16(
    const u16* __restrict__ A, const u16* __restrict__ Wt,
    const float* __restrict__ bias, const float* __restrict__ res,
    float* __restrict__ out, u16* __restrict__ out_bf, int M, int N, int K)
{
    __shared__ u16 As[2][128*72];   // [row][k 0..63], stride 72 (bank-safe)
    __shared__ u16 Bs[2][64*72];
    const int tid  = threadIdx.x;
    const int lane = tid & 63;
    const int w    = tid >> 6;          // 0..7
    const int mp   = w >> 1;
    const int np   = w & 1;
    const int m0   = blockIdx.x * 128;
    const int n0   = blockIdx.y * 64;
    const int fr   = lane & 15, fg = lane >> 4;
    const int ar   = tid >> 2, ac = tid & 3;     // A: 128 rows x (2x 8-chunk)
    const int br   = tid >> 3, bc = tid & 7;     // B: 64 rows x 8 chunks

    const u16* pa = A  + (size_t)(m0 + ar)*K + ac*8;
    const u16* pb = Wt + (size_t)(n0 + br)*K + bc*8;
    const int ns = K >> 6;                      // 5 or 20

    // direct-stage step 0
    *(u16x8*)&As[0][ar*72 + ac*8]      = *(const u16x8*)pa;
    *(u16x8*)&As[0][ar*72 + 32 + ac*8] = *(const u16x8*)(pa + 32);
    *(u16x8*)&Bs[0][br*72 + bc*8]      = *(const u16x8*)pb;
    // prefetch: r = step 1, s = step 2
    u16x8 ra0 = {}, ra1 = {}, rb = {};
    u16x8 sa0 = {}, sa1 = {}, sb = {};
    if (1 < ns) {
        ra0 = *(const u16x8*)(pa + 64);
        ra1 = *(const u16x8*)(pa + 96);
        rb  = *(const u16x8*)(pb + 64);
    }
    if (2 < ns) {
        sa0 = *(const u16x8*)(pa + 128);
        sa1 = *(const u16x8*)(pa + 160);
        sb  = *(const u16x8*)(pb + 128);
    }

    f32x4 acc[2][2] = {};
    for (int s = 0; s < ns; ++s) {
        __syncthreads();                 // buf[s&1] ready; compute(s-1) done
        const int cb = s & 1, nb = cb ^ 1;
        if (s + 1 < ns) {
            *(u16x8*)&As[nb][ar*72 + ac*8]      = ra0;
            *(u16x8*)&As[nb][ar*72 + 32 + ac*8] = ra1;
            *(u16x8*)&Bs[nb][br*72 + bc*8]      = rb;
            ra0 = sa0; ra1 = sa1; rb = sb;
            if (s + 3 < ns) {
                sa0 = *(const u16x8*)(pa + 64*(s+3));
                sa1 = *(const u16x8*)(pa + 64*(s+3) + 32);
                sb  = *(const u16x8*)(pb + 64*(s+3));
            }
        }
        #pragma unroll
        for (int c = 0; c < 2; ++c) {
            bf16x8 a0 = *(const bf16x8*)&As[cb][(mp*32      + fr)*72 + c*32 + fg*8];
            bf16x8 a1 = *(const bf16x8*)&As[cb][(mp*32 + 16 + fr)*72 + c*32 + fg*8];
            #pragma unroll
            for (int t = 0; t < 2; ++t) {
                bf16x8 b = *(const bf16x8*)&Bs[cb][((np*2+t)*16 + fr)*72 + c*32 + fg*8];
                acc[0][t] = __builtin_amdgcn_mfma_f32_16x16x32_bf16(a0, b, acc[0][t], 0, 0, 0);
                acc[1][t] = __builtin_amdgcn_mfma_f32_16x16x32_bf16(a1, b, acc[1][t], 0, 0, 0);
            }
        }
    }
    #pragma unroll
    for (int at = 0; at < 2; ++at) {
        #pragma unroll
        for (int t = 0; t < 2; ++t) {
            int gn = n0 + (np*2+t)*16 + fr;
            float bv = bias ? bias[gn] : 0.f;
            #pragma unroll
            for (int i = 0; i < 4; ++i) {
                int gm = m0 + mp*32 + at*16 + fg*4 + i;
                float v = acc[at][t][i] + bv;
                if (res) v += res[(size_t)gm*N + gn];
                if (out) out[(size_t)gm*N + gn] = v;
                if (out_bf) out_bf[(size_t)gm*N + gn] = f2b(v);
            }
        }
    }
}

// --------- QKV GEMM (bf16 A) + merged ctx K/V GEMM, one 1060-block launch.
// blocks 0..959: Q,K -> out_bf[8192][960] (cols 0..639); V (cols 640..959)
// written DIRECTLY TRANSPOSED to vt_self[(b*320+c)*1024 + p].
// blocks 960..1059: ctx K/V. m = bi&63 (XCD locality). BK=32 (occupancy-bound).
__global__ __launch_bounds__(512) void gemm_qkv_ctx(
    const u16* __restrict__ A, const u16* __restrict__ Wt,
    u16* __restrict__ out_bf, u16* __restrict__ vt_self,
    const u16* __restrict__ ctx, const u16* __restrict__ wk,
    const u16* __restrict__ wv, u16* __restrict__ kout, u16* __restrict__ vout)
{
    __shared__ u16 As[2][128*40];
    __shared__ u16 Bs[2][64*40];
    const int tid  = threadIdx.x;
    const int lane = tid & 63;
    const int w    = tid >> 6;
    const int fr   = lane & 15, fg = lane >> 4;
    const int bi   = blockIdx.x;

    if (bi < 960) {
        const int K  = Cch, N = 960;
        const int m0 = (bi & 63)*128;        // m fastest -> same XCD per m
        const int n0 = (bi >> 6)*64;
        const int mp = w >> 1, np = w & 1;
        const int ar = tid >> 2, ac = tid & 3;
        const bool hasB = tid < 256;

        const u16* pa = A  + (size_t)(m0 + ar)*K + ac*8;
        const u16* pb = Wt + (size_t)(n0 + ar)*K + ac*8;
        const int nk = K >> 5;                  // 10

        *(u16x8*)&As[0][ar*40 + ac*8] = *(const u16x8*)pa;
        if (hasB) *(u16x8*)&Bs[0][ar*40 + ac*8] = *(const u16x8*)pb;
        u16x8 xa = *(const u16x8*)(pa + 32);
        u16x8 ya = *(const u16x8*)(pa + 64);
        u16x8 xb = {}, yb = {};
        if (hasB) { xb = *(const u16x8*)(pb + 32); yb = *(const u16x8*)(pb + 64); }

        f32x4 acc[2][2] = {};
        for (int i = 0; i < nk; i += 2) {
            __syncthreads();
            *(u16x8*)&As[1][ar*40 + ac*8] = xa;
            if (hasB) *(u16x8*)&Bs[1][ar*40 + ac*8] = xb;
            if (i + 3 < nk) {
                xa = *(const u16x8*)(pa + 32*(i+3));
                if (hasB) xb = *(const u16x8*)(pb + 32*(i+3));
            }
            {
                bf16x8 a0 = *(const bf16x8*)&As[0][(mp*32      + fr)*40 + fg*8];
                bf16x8 a1 = *(const bf16x8*)&As[0][(mp*32 + 16 + fr)*40 + fg*8];
                #pragma unroll
                for (int t = 0; t < 2; ++t) {
                    bf16x8 b = *(const bf16x8*)&Bs[0][((np*2+t)*16 + fr)*40 + fg*8];
                    acc[0][t] = __builtin_amdgcn_mfma_f32_16x16x32_bf16(a0, b, acc[0][t], 0, 0, 0);
                    acc[1][t] = __builtin_amdgcn_mfma_f32_16x16x32_bf16(a1, b, acc[1][t], 0, 0, 0);
                }
            }
            __syncthreads();
            if (i + 2 < nk) {
                *(u16x8*)&As[0][ar*40 + ac*8] = ya;
                if (hasB) *(u16x8*)&Bs[0][ar*40 + ac*8] = yb;
                if (i + 4 < nk) {
                    ya = *(const u16x8*)(pa + 32*(i+4));
                    if (hasB) yb = *(const u16x8*)(pb + 32*(i+4));
                }
            }
            {
                bf16x8 a0 = *(const bf16x8*)&As[1][(mp*32      + fr)*40 + fg*8];
                bf16x8 a1 = *(const bf16x8*)&As[1][(mp*32 + 16 + fr)*40 + fg*8];
                #pragma unroll
                for (int t = 0; t < 2; ++t) {
                    bf16x8 b = *(const bf16x8*)&Bs[1][((np*2+t)*16 + fr)*40 + fg*8];
                    acc[0][t] = __builtin_amdgcn_mfma_f32_16x16x32_bf16(a0, b, acc[0][t], 0, 0, 0);
                    acc[1][t] = __builtin_amdgcn_mfma_f32_16x16x32_bf16(a1, b, acc[1][t], 0, 0, 0);
                }
            }
        }
        if (n0 < 640) {                       // Q,K: token-major
            #pragma unroll
            for (int at = 0; at < 2; ++at) {
                #pragma unroll
                for (int t = 0; t < 2; ++t) {
                    int gn = n0 + (np*2+t)*16 + fr;
                    #pragma unroll
                    for (int i = 0; i < 4; ++i) {
                        int gm = m0 + mp*32 + at*16 + fg*4 + i;
                        out_bf[(size_t)gm*N + gn] = f2b(acc[at][t][i]);
                    }
                }
            }
        } else {                              // V: write V^T directly
            #pragma unroll
            for (int at = 0; at < 2; ++at) {
                #pragma unroll
                for (int t = 0; t < 2; ++t) {
                    int c  = n0 - 640 + (np*2+t)*16 + fr;   // 0..319
                    int gm0 = m0 + mp*32 + at*16 + fg*4;    // multiple of 4
                    int b  = gm0 >> 10;
                    int p  = gm0 & (HW-1);
                    u16x4 vv;
                    #pragma unroll
                    for (int i = 0; i < 4; ++i) vv[i] = f2b(acc[at][t][i]);
                    *(u16x4*)&vt_self[((size_t)(b*Cch + c))*HW + p] = vv;
                }
            }
        }
        return;
    }

    // ---------------- merged ctx K/V path (blocks 960..1059) --------------
    {
        int cb = bi - 960;                   // 0..99
        const int z  = cb / 50; cb -= z*50;
        const int my = cb / 5, nx0 = cb - my*5;
        const int m0 = my*64, n0 = nx0*64;
        const u16* Wt2 = z ? wv : wk;
        u16* outp      = z ? vout : kout;
        const int mg = w >> 1;
        const int np = w & 1;
        const bool isA = tid < 256;
        const int cr = (tid & 255) >> 2, cc = tid & 3;

        const u16* ps = isA ? ctx + (size_t)(m0 + cr)*CTXD + cc*8
                            : Wt2 + (size_t)(n0 + cr)*CTXD + cc*8;
        u16* s0 = isA ? &As[0][cr*40 + cc*8] : &Bs[0][cr*40 + cc*8];
        u16* s1 = isA ? &As[1][cr*40 + cc*8] : &Bs[1][cr*40 + cc*8];
        const int nk = CTXD >> 5;    // 24

        *(u16x8*)s0 = *(const u16x8*)ps;
        u16x8 xv = *(const u16x8*)(ps + 32);
        u16x8 yv = *(const u16x8*)(ps + 64);

        f32x4 acc[2] = {};
        for (int i = 0; i < nk; i += 2) {
            __syncthreads();
            *(u16x8*)s1 = xv;
            if (i + 3 < nk) xv = *(const u16x8*)(ps + 32*(i+3));
            {
                bf16x8 a = *(const bf16x8*)&As[0][(mg*16 + fr)*40 + fg*8];
                #pragma unroll
                for (int t = 0; t < 2; ++t) {
                    bf16x8 b = *(const bf16x8*)&Bs[0][((np*2+t)*16 + fr)*40 + fg*8];
                    acc[t] = __builtin_amdgcn_mfma_f32_16x16x32_bf16(a, b, acc[t], 0, 0, 0);
                }
            }
            __syncthreads();
            if (i + 2 < nk) {
                *(u16x8*)s0 = yv;
                if (i + 4 < nk) yv = *(const u16x8*)(ps + 32*(i+4));
            }
            {
                bf16x8 a = *(const bf16x8*)&As[1][(mg*16 + fr)*40 + fg*8];
                #pragma unroll
                for (int t = 0; t < 2; ++t) {
                    bf16x8 b = *(const bf16x8*)&Bs[1][((np*2+t)*16 + fr)*40 + fg*8];
                    acc[t] = __builtin_amdgcn_mfma_f32_16x16x32_bf16(a, b, acc[t], 0, 0, 0);
                }
            }
        }
        #pragma unroll
        for (int t = 0; t < 2; ++t) {
            int gn = n0 + (np*2+t)*16 + fr;
            #pragma unroll
            for (int i = 0; i < 4; ++i) {
                int gm = m0 + mg*16 + fg*4 + i;
                if (gm < MCTX)
                    outp[(size_t)gm*Cch + gn] = f2b(acc[t][i]);
            }
        }
    }
}

// ---- proj_out GEMM + transpose + residual, BK=64 depth-3 pipeline (ns=5)
__global__ __launch_bounds__(512) void gemm_pout(
    const u16* __restrict__ A, const u16* __restrict__ Wt,
    const float* __restrict__ bias, const float* __restrict__ x,
    float* __restrict__ out, int K)
{
    __shared__ u16 As[2][128*72];
    __shared__ u16 Bs[2][64*72];
    const int tid  = threadIdx.x;
    const int lane = tid & 63;
    const int w    = tid >> 6;
    const int mp   = w >> 1;
    const int np   = w & 1;
    const int m0   = blockIdx.x * 128;
    const int n0   = blockIdx.y * 64;
    const int fr   = lane & 15, fg = lane >> 4;
    const int ar   = tid >> 2, ac = tid & 3;
    const int br   = tid >> 3, bc = tid & 7;

    const u16* pa = A  + (size_t)(m0 + ar)*K + ac*8;
    const u16* pb = Wt + (size_t)(n0 + br)*K + bc*8;
    const int ns = K >> 6;                      // 5

    *(u16x8*)&As[0][ar*72 + ac*8]      = *(const u16x8*)pa;
    *(u16x8*)&As[0][ar*72 + 32 + ac*8] = *(const u16x8*)(pa + 32);
    *(u16x8*)&Bs[0][br*72 + bc*8]      = *(const u16x8*)pb;
    u16x8 ra0 = {}, ra1 = {}, rb = {};
    u16x8 sa0 = {}, sa1 = {}, sb = {};
    if (1 < ns) {
        ra0 = *(const u16x8*)(pa + 64);
        ra1 = *(const u16x8*)(pa + 96);
        rb  = *(const u16x8*)(pb + 64);
    }
    if (2 < ns) {
        sa0 = *(const u16x8*)(pa + 128);
        sa1 = *(const u16x8*)(pa + 160);
        sb  = *(const u16x8*)(pb + 128);
    }

    f32x4 acc[2][2] = {};
    for (int s = 0; s < ns; ++s) {
        __syncthreads();
        const int cb = s & 1, nb = cb ^ 1;
        if (s + 1 < ns) {
            *(u16x8*)&As[nb][ar*72 + ac*8]      = ra0;
            *(u16x8*)&As[nb][ar*72 + 32 + ac*8] = ra1;
            *(u16x8*)&Bs[nb][br*72 + bc*8]      = rb;
            ra0 = sa0; ra1 = sa1; rb = sb;
            if (s + 3 < ns) {
                sa0 = *(const u16x8*)(pa + 64*(s+3));
                sa1 = *(const u16x8*)(pa + 64*(s+3) + 32);
                sb  = *(const u16x8*)(pb + 64*(s+3));
            }
        }
        #pragma unroll
        for (int c = 0; c < 2; ++c) {
            bf16x8 a0 = *(const bf16x8*)&As[cb][(mp*32      + fr)*72 + c*32 + fg*8];
            bf16x8 a1 = *(const bf16x8*)&As[cb][(mp*32 + 16 + fr)*72 + c*32 + fg*8];
            #pragma unroll
            for (int t = 0; t < 2; ++t) {
                bf16x8 b = *(const bf16x8*)&Bs[cb][((np*2+t)*16 + fr)*72 + c*32 + fg*8];
                acc[0][t] = __builtin_amdgcn_mfma_f32_16x16x32_bf16(a0, b, acc[0][t], 0, 0, 0);
                acc[1][t] = __builtin_amdgcn_mfma_f32_16x16x32_bf16(a1, b, acc[1][t], 0, 0, 0);
            }
        }
    }
    #pragma unroll
    for (int at = 0; at < 2; ++at) {
        #pragma unroll
        for (int t = 0; t < 2; ++t) {
            int gn = n0 + (np*2+t)*16 + fr;
            float bv = bias[gn];
            int gm0 = m0 + mp*32 + at*16 + fg*4;     // multiple of 4
            int b   = gm0 >> 10;
            int pcol= gm0 & (HW-1);
            size_t o = ((size_t)(b*Cch + gn))*HW + pcol;
            f32x4 xv = *(const f32x4*)&x[o];
            f32x4 vv;
            #pragma unroll
            for (int i = 0; i < 4; ++i) vv[i] = acc[at][t][i] + bv + xv[i];
            *(f32x4*)&out[o] = vv;
        }
    }
}

// ---- GEGLU fused MFMA GEMM. 512 threads / 8 waves, each wave 32x32 with
// both a- and g-accumulators (8 MFMA/chunk). Grid (m,n): m fastest. BK=32.
__global__ __launch_bounds__(512) void geglu_bf16(
    const u16* __restrict__ A, const u16* __restrict__ Wt,
    const float* __restrict__ b1, u16* __restrict__ out, int M, int K)
{
    __shared__ u16 As[2][128*40];
    __shared__ u16 Ba[2][64*40];
    __shared__ u16 Bg[2][64*40];
    const int tid  = threadIdx.x;
    const int lane = tid & 63;
    const int w    = tid >> 6;
    const int mp   = w >> 1;            // 0..3
    const int np   = w & 1;
    const int m0   = blockIdx.x * 128;   // m fastest (XCD locality)
    const int n0   = blockIdx.y * 64;
    const int fr   = lane & 15, fg = lane >> 4;
    const int ar   = tid >> 2, ac = tid & 3;     // 0..127 rows, 4 chunks
    const int nk   = K >> 5;   // 10

    const u16* pa = A + (size_t)(m0 + ar)*K + ac*8;
    // B rows 0..63 -> Ba, 64..127 -> Bg (at Wt row FFI + n0 + ..)
    const int bq = (ar < 64) ? (n0 + ar) : (FFI + n0 + ar - 64);
    const u16* pb = Wt + (size_t)bq*K + ac*8;
    u16* bs0 = (ar < 64) ? &Ba[0][ar*40 + ac*8] : &Bg[0][(ar-64)*40 + ac*8];
    u16* bs1 = (ar < 64) ? &Ba[1][ar*40 + ac*8] : &Bg[1][(ar-64)*40 + ac*8];

    *(u16x8*)&As[0][ar*40 + ac*8] = *(const u16x8*)pa;
    *(u16x8*)bs0 = *(const u16x8*)pb;
    u16x8 xa = *(const u16x8*)(pa + 32);
    u16x8 xb = *(const u16x8*)(pb + 32);
    u16x8 ya = *(const u16x8*)(pa + 64);
    u16x8 yb = *(const u16x8*)(pb + 64);

    f32x4 aca[2][2] = {}, acg[2][2] = {};
    for (int i = 0; i < nk; i += 2) {
        __syncthreads();
        *(u16x8*)&As[1][ar*40 + ac*8] = xa;
        *(u16x8*)bs1 = xb;
        if (i + 3 < nk) {
            xa = *(const u16x8*)(pa + 32*(i+3));
            xb = *(const u16x8*)(pb + 32*(i+3));
        }
        {
            bf16x8 a0 = *(const bf16x8*)&As[0][(mp*32      + fr)*40 + fg*8];
            bf16x8 a1 = *(const bf16x8*)&As[0][(mp*32 + 16 + fr)*40 + fg*8];
            #pragma unroll
            for (int t = 0; t < 2; ++t) {
                bf16x8 ba = *(const bf16x8*)&Ba[0][((np*2+t)*16 + fr)*40 + fg*8];
                bf16x8 bg = *(const bf16x8*)&Bg[0][((np*2+t)*16 + fr)*40 + fg*8];
                aca[0][t] = __builtin_amdgcn_mfma_f32_16x16x32_bf16(a0, ba, aca[0][t], 0, 0, 0);
                aca[1][t] = __builtin_amdgcn_mfma_f32_16x16x32_bf16(a1, ba, aca[1][t], 0, 0, 0);
                acg[0][t] = __builtin_amdgcn_mfma_f32_16x16x32_bf16(a0, bg, acg[0][t], 0, 0, 0);
                acg[1][t] = __builtin_amdgcn_mfma_f32_16x16x32_bf16(a1, bg, acg[1][t], 0, 0, 0);
            }
        }
        __syncthreads();
        if (i + 2 < nk) {
            *(u16x8*)&As[0][ar*40 + ac*8] = ya;
            *(u16x8*)bs0 = yb;
            if (i + 4 < nk) {
                ya = *(const u16x8*)(pa + 32*(i+4));
                yb = *(const u16x8*)(pb + 32*(i+4));
            }
        }
        {
            bf16x8 a0 = *(const bf16x8*)&As[1][(mp*32      + fr)*40 + fg*8];
            bf16x8 a1 = *(const bf16x8*)&As[1][(mp*32 + 16 + fr)*40 + fg*8];
            #pragma unroll
            for (int t = 0; t < 2; ++t) {
                bf16x8 ba = *(const bf16x8*)&Ba[1][((np*2+t)*16 + fr)*40 + fg*8];
                bf16x8 bg = *(const bf16x8*)&Bg[1][((np*2+t)*16 + fr)*40 + fg*8];
                aca[0][t] = __builtin_amdgcn_mfma_f32_16x16x32_bf16(a0, ba, aca[0][t], 0, 0, 0);
                aca[1][t] = __builtin_amdgcn_mfma_f32_16x16x32_bf16(a1, ba, aca[1][t], 0, 0, 0);
                acg[0][t] = __builtin_amdgcn_mfma_f32_16x16x32_bf16(a0, bg, acg[0][t], 0, 0, 0);
                acg[1][t] = __builtin_amdgcn_mfma_f32_16x16x32_bf16(a1, bg, acg[1][t], 0, 0, 0);
            }
        }
    }
    #pragma unroll
    for (int at = 0; at < 2; ++at) {
        #pragma unroll
        for (int t = 0; t < 2; ++t) {
            int gn = n0 + (np*2+t)*16 + fr;
            float ba = b1[gn], bg = b1[FFI + gn];
            #pragma unroll
            for (int i = 0; i < 4; ++i) {
                int gm = m0 + mp*32 + at*16 + fg*4 + i;
                float av = aca[at][t][i] + ba;
                float gv = acg[at][t][i] + bg;
                float gel = 0.5f*gv*(1.f + erff(gv*0.70710678118654752f));
                out[(size_t)gm*FFI + gn] = f2b(av*gel);
            }
        }
    }
}

// ------------------------------------------------------- MFMA flash attention
// 512 threads / 8 waves, 128-query tiles, double-buffered K/V LDS
// (1 barrier per KV tile), register prefetch, XCD-aware 1-D block decode.
// Q weights pre-scaled by 1/sqrt(40)*log2(e): P = exp2(S) == exp(S_orig).
// Blocks 0..511: attention; blocks 512+: cross-V transpose tail.
__global__ __launch_bounds__(512) void flash_mfma(
    const u16* __restrict__ qb, int qstride,
    const u16* __restrict__ kb, int kstride,
    const u16* __restrict__ vt, int vstride,
    const u64* __restrict__ mbits, int nw,
    u16* __restrict__ out,        // [B*HW][320]
    int Lkv,
    const u16* __restrict__ tin, u16* __restrict__ tout)
{
    __shared__ u16 QPs[128*72];   // Q (stride 72) then P (stride 68), per-wave rows
    __shared__ u16 Ks[2][64*72];
    __shared__ u16 Vs[2][48*72];  // [d][key], row 40 = ones, 41..47 zero

    const int tid  = threadIdx.x;
    const int bi   = blockIdx.x;

    if (bi >= 512) {                        // cross-V transpose tail blocks
        int cb = bi - 512;                  // 0..79
        const int c0 = (cb % 5)*64;
        const int t0 = ((cb/5) & 1)*64;
        const int b  = cb/10;
        {   // stage 64x64 tile, XOR-swizzled 16B chunks (reuse QPs)
            int r = tid >> 3, ch2 = tid & 7;   // 512 threads = 64 rows x 8 chunks
            u16x8 val = {};
            if (t0 + r < CTXL)
                val = *(const u16x8*)(tin + ((size_t)(b*CTXL + t0 + r))*Cch + c0 + ch2*8);
            *(u16x8*)&QPs[r*72 + (ch2 ^ (r & 7))*8] = val;
        }
        __syncthreads();
        for (int e = tid; e < 4096; e += 512) {
            int c = e >> 6, t = e & 63;
            u16 v = QPs[t*72 + (((c >> 3) ^ (t & 7))*8) + (c & 7)];
            tout[((size_t)(b*Cch + c0 + c))*128 + t0 + t] = v;
        }
        return;
    }

    const int lane = tid & 63;
    const int w    = tid >> 6;            // 0..7
    const int col  = lane & 15;
    const int quad = lane >> 4;
    const int hb   = (bi & 7)*8 + (bi >> 6);  // 0..63
    const int qt   = (bi >> 3) & 7;
    const int h    = hb & 7;
    const int b    = hb >> 3;                 // == bi&7
    const int q0   = qt*128;
    const int ch   = tid & 7;
    const int r0   = tid >> 3;            // 0..63

    // stage Q tile rows r0, r0+64 (zero-padded d 40..63), stride 72
    {
        const u16* qT = qb + ((size_t)(b*HW + q0))*qstride + (size_t)h*DHEAD + ch*8;
        u16x8 v0 = {}, v1 = {};
        if (ch < 5) {
            v0 = *(const u16x8*)(qT + (size_t)r0*qstride);
            v1 = *(const u16x8*)(qT + (size_t)(r0+64)*qstride);
        }
        *(u16x8*)&QPs[r0*72 + ch*8]      = v0;
        *(u16x8*)&QPs[(r0+64)*72 + ch*8] = v1;
    }
    // constant V rows 40..47 in BOTH buffers (row 40 = ones)
    if (tid < 128) {
        int rr  = tid >> 3;               // 0..15
        int row = 40 + (rr & 7);
        int buf = rr >> 3;
        u16x8 v = {};
        if (row == DHEAD) {
            #pragma unroll
            for (int z = 0; z < 8; ++z) v[z] = 0x3F80;   // bf16 1.0
        }
        *(u16x8*)&Vs[buf][row*72 + ch*8] = v;
    }

    // incremental row pointers (bumped by 64 keys per tile)
    const bool kok = ch < 5;
    const u16* kR = kb + (size_t)b*Lkv*kstride + (size_t)h*DHEAD + ch*8
                       + (size_t)r0*kstride;
    const u16* vR = vt + ((size_t)(b*Cch + h*DHEAD))*vstride + ch*8
                       + (size_t)r0*vstride;
    const bool vok = r0 < DHEAD;
    const u64* mrow = mbits + ((size_t)(b*HW + q0 + w*16 + quad*4))*nw;

    // register-prefetch tile 0
    u16x8 nk = {}, nv = {};
    if (kok && r0 < Lkv) nk = *(const u16x8*)kR;
    if (vok) nv = *(const u16x8*)vR;

    __syncthreads();
    const bf16x8 qa0 = *(const bf16x8*)&QPs[(w*16 + col)*72 +  0 + quad*8];
    const bf16x8 qa1 = *(const bf16x8*)&QPs[(w*16 + col)*72 + 32 + quad*8];

    f32x4 acc_o[3] = {};

    const int nkt = (Lkv + 63) / 64;
    int cur = 0;
    for (int jt = 0; jt < nkt; ++jt) {
        // write prefetched tile -> buf[cur]
        *(u16x8*)&Ks[cur][r0*72 + ch*8] = nk;
        if (vok) *(u16x8*)&Vs[cur][r0*72 + ch*8] = nv;
        if (jt + 1 < nkt) {                // prefetch next tile (overlaps compute)
            kR += (size_t)64*kstride;
            vR += 64;
            nk = (u16x8){};
            if (kok && ((jt+1)*64 + r0 < Lkv)) nk = *(const u16x8*)kR;
            if (vok) nv = *(const u16x8*)vR;
        }
        __syncthreads();

        // mask words (latency overlaps MFMA below)
        u64 mw[4];
        #pragma unroll
        for (int i = 0; i < 4; ++i) mw[i] = mrow[i*nw + jt];

        // S = Q K^T (prescaled, log2 domain)
        f32x4 s[4] = {};
        #pragma unroll
        for (int nt = 0; nt < 4; ++nt) {
            bf16x8 b0 = *(const bf16x8*)&Ks[cur][(nt*16 + col)*72 +  0 + quad*8];
            bf16x8 b1 = *(const bf16x8*)&Ks[cur][(nt*16 + col)*72 + 32 + quad*8];
            s[nt] = __builtin_amdgcn_mfma_f32_16x16x32_bf16(qa0, b0, s[nt], 0, 0, 0);
            s[nt] = __builtin_amdgcn_mfma_f32_16x16x32_bf16(qa1, b1, s[nt], 0, 0, 0);
        }

        // P = exp2(S) (no shift), zero masked keys
        #pragma unroll
        for (int i = 0; i < 4; ++i) {
            #pragma unroll
            for (int nt = 0; nt < 4; ++nt) {
                float p = __builtin_amdgcn_exp2f(s[nt][i]);
                unsigned bits = (unsigned)(mw[i] >> (nt*16));
                s[nt][i] = ((bits >> col) & 1u) ? p : 0.f;
            }
        }

        // P -> LDS, stride 68 (per-wave rows, no cross-wave sharing)
        #pragma unroll
        for (int nt = 0; nt < 4; ++nt)
            #pragma unroll
            for (int i = 0; i < 4; ++i)
                QPs[(w*16 + quad*4 + i)*68 + nt*16 + col] =
                    (u16)(__float_as_uint(s[nt][i]) >> 16);

        // O += P V   (col 40 accumulates l)
        bf16x8 pa0, pa1;
        __builtin_memcpy(&pa0, &QPs[(w*16 + col)*68 +  0 + quad*8], 16);
        __builtin_memcpy(&pa1, &QPs[(w*16 + col)*68 + 32 + quad*8], 16);
        #pragma unroll
        for (int nt = 0; nt < 3; ++nt) {
            bf16x8 vb0 = *(const bf16x8*)&Vs[cur][(nt*16 + col)*72 +  0 + quad*8];
            bf16x8 vb1 = *(const bf16x8*)&Vs[cur][(nt*16 + col)*72 + 32 + quad*8];
            acc_o[nt] = __builtin_amdgcn_mfma_f32_16x16x32_bf16(pa0, vb0, acc_o[nt], 0, 0, 0);
            acc_o[nt] = __builtin_amdgcn_mfma_f32_16x16x32_bf16(pa1, vb1, acc_o[nt], 0, 0, 0);
        }
        cur ^= 1;
    }

    // l_i lives in acc_o[2] at col 40 (lane col==8 of each 16-group)
    float inv_l[4];
    #pragma unroll
    for (int i = 0; i < 4; ++i)
        inv_l[i] = 1.f / __shfl(acc_o[2][i], (lane & 48) | 8);

    #pragma unroll
    for (int nt = 0; nt < 3; ++nt) {
        int d = nt*16 + col;
        if (d < DHEAD) {
            #pragma unroll
            for (int i = 0; i < 4; ++i) {
                int q = q0 + w*16 + quad*4 + i;
                out[((size_t)(b*HW + q))*Cch + h*DHEAD + d] = f2b(acc_o[nt][i] * inv_l[i]);
            }
        }
    }
}

// ---------------------------------------------------------------------------
extern "C" void kernel_launch(void* const* d_in, const int* in_sizes, int n_in,
                              void* d_out, int out_size, void* d_ws, size_t ws_size,
                              hipStream_t stream)
{
    const float* x        = (const float*)d_in[0];
    const float* context  = (const float*)d_in[1];
    const void*  vis_mask = d_in[2];
    const void*  v2t_mask = d_in[3];
    const float* gn_s     = (const float*)d_in[4];
    const float* gn_b     = (const float*)d_in[5];
    const float* proj_in_w= (const float*)d_in[6];
    const float* proj_in_b= (const float*)d_in[7];
    const float* n1_s     = (const float*)d_in[8];
    const float* n1_b     = (const float*)d_in[9];
    const float* wq1      = (const float*)d_in[10];
    const float* wk1      = (const float*)d_in[11];
    const float* wv1      = (const float*)d_in[12];
    const float* wo1      = (const float*)d_in[13];
    const float* bo1      = (const float*)d_in[14];
    const float* n2_s     = (const float*)d_in[15];
    const float* n2_b     = (const float*)d_in[16];
    const float* wq2      = (const float*)d_in[17];
    const float* wk2      = (const float*)d_in[18];
    const float* wv2      = (const float*)d_in[19];
    const float* wo2      = (const float*)d_in[20];
    const float* bo2      = (const float*)d_in[21];
    const float* n3_s     = (const float*)d_in[22];
    const float* n3_b     = (const float*)d_in[23];
    const float* ff_w1    = (const float*)d_in[24];
    const float* ff_b1    = (const float*)d_in[25];
    const float* ff_w2    = (const float*)d_in[26];
    const float* ff_b2    = (const float*)d_in[27];
    const float* pout_w   = (const float*)d_in[28];
    const float* pout_b   = (const float*)d_in[29];
    float* out = (float*)d_out;

    const size_t TOKC = (size_t)NTOK*Cch;        // 2,621,440
    float* ws   = (float*)d_ws;
    float* Hb   = ws;                            // fp32 residual spine
    u16*   QKV  = (u16*)(Hb + TOKC);             // [8192][960] packed, 3*TOKC
    u16*   Vt_g = QKV + 3*TOKC;                  // self V^T, TOKC
    u16*   G_bf = QKV;                           // FF reuse (4*TOKC)
    u16*   T0b  = Vt_g + TOKC;                   // GN/LN out, TOKC
    u16*   T1b  = T0b + TOKC;                    // attn out, TOKC
    u16*   Hb_bf= T1b + TOKC;                    // bf16 mirror post-FF, TOKC
    u16*   Wbf  = Hb_bf + TOKC;                  // 2,539,520 u16
    u64*   mb_vis = (u64*)(Wbf + 2539520);       // 8192*16 u64
    u64*   mb_v2t = mb_vis + 131072;             // 8192*2  u64
    u16*   ctx_bf = (u16*)(mb_v2t + 16384);      // 640*768 u16
    u16*   Kc_bf  = ctx_bf + MCTXP*CTXD;         // ctx K, 616*320 (pad 640)
    u16*   Vc_bf  = Kc_bf + 640*Cch;             // ctx V
    float* gnA    = (float*)(Vc_bf + 640*Cch);   // 8*320 floats
    float* gnB    = gnA + Bsz*Cch;
    u16*   Vt_x   = (u16*)(gnB + Bsz*Cch);       // cross V^T, 8*320*128 u16

    u16* w_q1  = Wbf;                            // q1|k1|v1 contiguous [960][320]
    u16* w_k1  = Wbf +  102400;
    u16* w_v1  = Wbf +  204800;
    u16* w_pin = Wbf +  307200;
    u16* w_o1  = Wbf +  409600;
    u16* w_q2  = Wbf +  512000;
    u16* w_o2  = Wbf +  614400;
    u16* w_ff1 = Wbf +  716800;
    u16* w_ff2 = Wbf + 1536000;
    u16* w_po  = Wbf + 1945600;
    u16* w_k2  = Wbf + 2048000;                  // [320][768]
    u16* w_v2  = Wbf + 2293760;

    // Q scale folds softmax 1/sqrt(40) AND log2(e) so flash uses exp2 directly
    const float qscale = 0.15811388300841897f * 1.4426950408889634f;
    WPack pack;
    pack.w[0]  = { wq1,       w_q1,  Cch, Cch, 25,  qscale };
    pack.w[1]  = { wk1,       w_k1,  Cch, Cch, 25,  1.f };
    pack.w[2]  = { wv1,       w_v1,  Cch, Cch, 25,  1.f };
    pack.w[3]  = { proj_in_w, w_pin, Cch, Cch, 25,  1.f };
    pack.w[4]  = { wo1,       w_o1,  Cch, Cch, 25,  1.f };
    pack.w[5]  = { wq2,       w_q2,  Cch, Cch, 25,  qscale };
    pack.w[6]  = { wo2,       w_o2,  Cch, Cch, 25,  1.f };
    pack.w[7]  = { ff_w1,     w_ff1, Cch, 2*FFI, 200, 1.f };
    pack.w[8]  = { ff_w2,     w_ff2, FFI, Cch, 100, 1.f };
    pack.w[9]  = { pout_w,    w_po,  Cch, Cch, 25,  1.f };
    pack.w[10] = { wk2,       w_k2,  CTXD, Cch, 60, 1.f };
    pack.w[11] = { wv2,       w_v2,  CTXD, Cch, 60, 1.f };
    // total tiles = 7*25 + 200 + 100 + 25 + 60 + 60 = 620 = WT_TILES

    dim3 blk256(256);
    dim3 blk512(512);
    dim3 gTok(NTOK/128, Cch/64);                 // (64,5)  m fastest
    dim3 gFF(NTOK/128, FFI/64);                  // (64,20) m fastest
    dim3 gGN(Cch/64, HW/64, Bsz);                // (5,16,8)

    // fused preamble: weight tiles | ctx | mask-bits(vis,v2t) | gn stats
    preamble<<<WT_TILES + CTXBLK + 4096 + 256, blk256, 0, stream>>>(
        pack, context, ctx_bf, vis_mask, v2t_mask, mb_vis, mb_v2t,
        x, gn_s, gn_b, gnA, gnB);

    gn_apply<<<gGN, blk256, 0, stream>>>(x, gnA, gnB, T0b);
    gemm_bf16<<<gTok, blk512, 0, stream>>>(T0b, w_pin, proj_in_b, nullptr, Hb, nullptr, NTOK, Cch, Cch);

    // --- self attention (QKV + ctx K/V in one launch; V^T written directly) ---
    layernorm_kernel<<<NTOK/4, blk256, 0, stream>>>(Hb, n1_s, n1_b, T0b);
    gemm_qkv_ctx<<<1060, blk512, 0, stream>>>(T0b, w_q1, QKV, Vt_g,
                                              ctx_bf, w_k2, w_v2, Kc_bf, Vc_bf);
    flash_mfma<<<512 + 80, blk512, 0, stream>>>(QKV, 960, QKV + 320, 960, Vt_g, HW,
                                                mb_vis, 16, T1b, HW, Vc_bf, Vt_x);
    gemm_bf16<<<gTok, blk512, 0, stream>>>(T1b, w_o1, bo1, Hb, Hb, nullptr, NTOK, Cch, Cch);

    // --- cross attention ---
    layernorm_kernel<<<NTOK/4, blk256, 0, stream>>>(Hb, n2_s, n2_b, T0b);
    gemm_bf16<<<gTok, blk512, 0, stream>>>(T0b, w_q2, nullptr, nullptr, nullptr, QKV, NTOK, Cch, Cch);
    flash_mfma<<<512, blk512, 0, stream>>>(QKV, Cch, Kc_bf, Cch, Vt_x, 128,
                                           mb_v2t, 2, T1b, CTXL, nullptr, nullptr);
    gemm_bf16<<<gTok, blk512, 0, stream>>>(T1b, w_o2, bo2, Hb, Hb, nullptr, NTOK, Cch, Cch);

    // --- GEGLU feed-forward ---
    layernorm_kernel<<<NTOK/4, blk256, 0, stream>>>(Hb, n3_s, n3_b, T0b);
    geglu_bf16<<<gFF, blk512, 0, stream>>>(T0b, w_ff1, ff_b1, G_bf, NTOK, Cch);
    gemm_bf16<<<gTok, blk512, 0, stream>>>(G_bf, w_ff2, ff_b2, Hb, nullptr, Hb_bf, NTOK, Cch, FFI);

    // --- proj_out + transpose + residual (fused) ---
    gemm_pout<<<gTok, blk512, 0, stream>>>(Hb_bf, w_po, pout_b, x, out, Cch);
}

// Round 11
// 340.626 us; speedup vs baseline: 1.0141x; 1.0141x over previous
//
#include <hip/hip_runtime.h>
#include <hip/hip_bf16.h>
#include <math.h>

// ---------------------------------------------------------------------------
// SpatialTransformer block. R24 = R22 exactly (revert R23's depth-3 register
// pipeline: it cost ~3us — extra VGPRs + reg-shuffle with no exposed latency
// to hide; depth-2 BK=64 is the structural floor for these L2-resident GEMMs).
// B=8, C=320, H=W=32 (HW=1024), HEADS=8, DHEAD=40, CTX=77x768, FF_INNER=1280.
// ---------------------------------------------------------------------------

#define Bsz   8
#define Cch   320
#define HW    1024
#define NTOK  (Bsz*HW)          // 8192
#define HEADS 8
#define DHEAD 40
#define CTXL  77
#define CTXD  768
#define FFI   1280
#define MCTX  (Bsz*CTXL)        // 616
#define MCTXP 640               // padded rows for ctx GEMM

typedef unsigned short u16;
typedef unsigned long long u64;
typedef __attribute__((ext_vector_type(8))) u16    u16x8;
typedef __attribute__((ext_vector_type(4))) u16    u16x4;
typedef __attribute__((ext_vector_type(8))) __bf16 bf16x8;
typedef __attribute__((ext_vector_type(4))) float  f32x4;

__device__ inline u16 f2b(float f) {            // fp32 -> bf16 RNE
    unsigned u = __float_as_uint(f);
    return (u16)((u + 0x7FFFu + ((u >> 16) & 1u)) >> 16);
}

// ------------------------- GroupNorm pass 2: normalize + CHW->token-major
__global__ __launch_bounds__(256) void gn_apply(
    const float* __restrict__ x, const float* __restrict__ gnA,
    const float* __restrict__ gnB, u16* __restrict__ out)
{
    __shared__ u16 T[64*72];
    const int tid = threadIdx.x;
    const int c0 = blockIdx.x * 64;
    const int p0 = blockIdx.y * 64;
    const int b  = blockIdx.z;
    for (int e = tid; e < 512; e += 256) {
        int r = e >> 3, ch = e & 7;
        const float* src = x + ((size_t)(b*Cch + c0 + r))*HW + p0 + ch*8;
        float a  = gnA[b*Cch + c0 + r];
        float bb = gnB[b*Cch + c0 + r];
        float4 v0 = *(const float4*)src;
        float4 v1 = *(const float4*)(src + 4);
        u16x8 val;
        val[0] = f2b(v0.x*a + bb); val[1] = f2b(v0.y*a + bb);
        val[2] = f2b(v0.z*a + bb); val[3] = f2b(v0.w*a + bb);
        val[4] = f2b(v1.x*a + bb); val[5] = f2b(v1.y*a + bb);
        val[6] = f2b(v1.z*a + bb); val[7] = f2b(v1.w*a + bb);
        *(u16x8*)&T[r*72 + (ch ^ (r & 7))*8] = val;
    }
    __syncthreads();
    for (int e = tid; e < 4096; e += 256) {
        int p = e >> 6, c = e & 63;
        u16 v = T[c*72 + (((p >> 3) ^ (c & 7))*8) + (p & 7)];
        out[((size_t)(b*HW + p0 + p))*Cch + c0 + c] = v;
    }
}

// ------------------------------------------------------- LayerNorm -> bf16
__global__ __launch_bounds__(256) void layernorm_kernel(
    const float* __restrict__ in, const float* __restrict__ s,
    const float* __restrict__ bgain, u16* __restrict__ out)
{
    int t = blockIdx.x*4 + (threadIdx.x >> 6);
    int lane = threadIdx.x & 63;
    const float* row = in + (size_t)t*Cch;
    float v[5];
    float sum = 0.f, sq = 0.f;
    #pragma unroll
    for (int i = 0; i < 5; ++i) {
        v[i] = row[lane + 64*i];
        sum += v[i]; sq += v[i]*v[i];
    }
    #pragma unroll
    for (int off = 32; off > 0; off >>= 1) {
        sum += __shfl_xor(sum, off);
        sq  += __shfl_xor(sq,  off);
    }
    float mean = sum * (1.f/320.f);
    float var  = sq  * (1.f/320.f) - mean*mean;
    float inv  = rsqrtf(var + 1e-5f);
    u16* orow = out + (size_t)t*Cch;
    #pragma unroll
    for (int i = 0; i < 5; ++i) {
        int c = lane + 64*i;
        orow[c] = f2b((v[i]-mean)*inv*s[c] + bgain[c]);
    }
}

// ------------- fused preamble: weights + ctx + mask bits + gn statistics
struct WDesc { const float* src; u16* dst; int K; int N; int tiles; float scl; };
struct WPack { WDesc w[12]; };

#define WT_TILES 620
#define CTXBLK   240     // 640*768 / 2048

__global__ __launch_bounds__(256) void preamble(
    WPack p, const float* __restrict__ ctxsrc, u16* __restrict__ ctxdst,
    const void* __restrict__ vis, const void* __restrict__ v2t,
    u64* __restrict__ bvis, u64* __restrict__ bv2t,
    const float* __restrict__ x, const float* __restrict__ gscale,
    const float* __restrict__ gbias, float* __restrict__ gnA,
    float* __restrict__ gnB)
{
    __shared__ u16 T[64*72];
    int blk = blockIdx.x;
    int tid = threadIdx.x;
    if (blk < WT_TILES) {                      // tiled weight transpose
        int t = blk;
        #pragma unroll
        for (int i = 0; i < 12; ++i) {
            int nt = p.w[i].tiles;
            if (t < nt) {
                const int K = p.w[i].K, N = p.w[i].N;
                const int ntN = N >> 6;
                const int tk = t / ntN, tn = t - tk*ntN;
                const float scl = p.w[i].scl;
                const float* src = p.w[i].src;
                u16* dst = p.w[i].dst;
                for (int e = tid; e < 512; e += 256) {
                    int r = e >> 3, ch = e & 7;
                    const float* sp = src + (size_t)(tk*64 + r)*N + tn*64 + ch*8;
                    float4 v0 = *(const float4*)sp;
                    float4 v1 = *(const float4*)(sp + 4);
                    u16x8 val;
                    val[0] = f2b(v0.x*scl); val[1] = f2b(v0.y*scl);
                    val[2] = f2b(v0.z*scl); val[3] = f2b(v0.w*scl);
                    val[4] = f2b(v1.x*scl); val[5] = f2b(v1.y*scl);
                    val[6] = f2b(v1.z*scl); val[7] = f2b(v1.w*scl);
                    *(u16x8*)&T[r*72 + (ch ^ (r & 7))*8] = val;
                }
                __syncthreads();
                for (int e = tid; e < 4096; e += 256) {
                    int n = e >> 6, k = e & 63;
                    u16 v = T[k*72 + (((n >> 3) ^ (k & 7))*8) + (n & 7)];
                    dst[(size_t)(tn*64 + n)*K + tk*64 + k] = v;
                }
                return;
            }
            t -= nt;
        }
        return;
    }
    if (blk < WT_TILES + CTXBLK) {             // ctx fp32 -> bf16 (padded)
        int idx = (blk - WT_TILES)*2048 + tid*8;
        int r = idx / CTXD;
        u16x8 val = {};
        if (r < MCTX) {
            float4 v0 = *(const float4*)(ctxsrc + idx);
            float4 v1 = *(const float4*)(ctxsrc + idx + 4);
            val[0] = f2b(v0.x); val[1] = f2b(v0.y);
            val[2] = f2b(v0.z); val[3] = f2b(v0.w);
            val[4] = f2b(v1.x); val[5] = f2b(v1.y);
            val[6] = f2b(v1.z); val[7] = f2b(v1.w);
        }
        *(u16x8*)(ctxdst + idx) = val;
        return;
    }
    if (blk >= WT_TILES + CTXBLK + 4096) {     // groupnorm statistics role
        int gb = blk - (WT_TILES + CTXBLK + 4096);   // 0..255
        int b = gb >> 5, g = gb & 31;
        __shared__ float rs[256], rq[256];
        const float4* xg = (const float4*)(x + ((size_t)b*Cch + g*10)*HW);
        float s = 0.f, q = 0.f;
        #pragma unroll
        for (int i = 0; i < 10; ++i) {
            float4 v = xg[tid + i*256];
            s += v.x + v.y + v.z + v.w;
            q += v.x*v.x + v.y*v.y + v.z*v.z + v.w*v.w;
        }
        rs[tid] = s; rq[tid] = q; __syncthreads();
        for (int off = 128; off > 0; off >>= 1) {
            if (tid < off) { rs[tid] += rs[tid+off]; rq[tid] += rq[tid+off]; }
            __syncthreads();
        }
        if (tid < 10) {
            float mean = rs[0] * (1.f/10240.f);
            float var  = rq[0] * (1.f/10240.f) - mean*mean;
            float inv  = rsqrtf(var + 1e-6f);
            int chn = g*10 + tid;
            float a = inv * gscale[chn];
            gnA[b*Cch + chn] = a;
            gnB[b*Cch + chn] = gbias[chn] - mean*a;
        }
        return;
    }
    // mask -> bit words; dtype probed from vis[0..4096)
    __shared__ int any;
    if (tid == 0) any = 0;
    __syncthreads();
    const unsigned char* probe = (const unsigned char*)vis;
    for (int i = tid; i < 4096; i += 256)
        if ((i & 3) && probe[i]) any = 1;
    __syncthreads();
    const int isU8 = any;
    int mb = blk - WT_TILES - CTXBLK;          // 0..4095
    const void* mask; u64* bits; int Lkv, nw;
    if (mb < 2048) { mask = vis; bits = bvis; Lkv = HW;   nw = 16; }
    else           { mask = v2t; bits = bv2t; Lkv = CTXL; nw = 2; mb -= 2048; }
    const int wv = tid >> 6, lane = tid & 63;
    const int row = mb*4 + wv;
    const unsigned char* m8  = (const unsigned char*)mask;
    const int*           m32 = (const int*)mask;
    const size_t base = (size_t)row * Lkv;
    for (int w = 0; w < nw; ++w) {
        int j = w*64 + lane;
        bool on = (j < Lkv) && (isU8 ? (m8[base+j] != 0) : (m32[base+j] != 0));
        u64 word = __ballot(on);
        if (lane == 0) bits[(size_t)row*nw + w] = word;
    }
}

// --------- bf16 MFMA GEMM, BK=64: 1 barrier per 64-wide K-step, depth-2.
// out[M,N] = A[M,K] @ Wt[N,K]^T (+bias)(+res). Block 128x64, 512 thr / 8 waves.
// Grid (m-blocks, n-blocks): m fastest (XCD locality). K must be mult of 64.
__global__ __launch_bounds__(512) void gemm_bf16(
    const u16* __restrict__ A, const u16* __restrict__ Wt,
    const float* __restrict__ bias, const float* __restrict__ res,
    float* __restrict__ out, u16* __restrict__ out_bf, int M, int N, int K)
{
    __shared__ u16 As[2][128*72];   // [row][k 0..63], stride 72 (bank-safe)
    __shared__ u16 Bs[2][64*72];
    const int tid  = threadIdx.x;
    const int lane = tid & 63;
    const int w    = tid >> 6;          // 0..7
    const int mp   = w >> 1;
    const int np   = w & 1;
    const int m0   = blockIdx.x * 128;
    const int n0   = blockIdx.y * 64;
    const int fr   = lane & 15, fg = lane >> 4;
    const int ar   = tid >> 2, ac = tid & 3;     // A: 128 rows x (2x 8-chunk)
    const int br   = tid >> 3, bc = tid & 7;     // B: 64 rows x 8 chunks

    const u16* pa = A  + (size_t)(m0 + ar)*K + ac*8;
    const u16* pb = Wt + (size_t)(n0 + br)*K + bc*8;
    const int ns = K >> 6;                      // 5 or 20

    // direct-stage step 0
    *(u16x8*)&As[0][ar*72 + ac*8]      = *(const u16x8*)pa;
    *(u16x8*)&As[0][ar*72 + 32 + ac*8] = *(const u16x8*)(pa + 32);
    *(u16x8*)&Bs[0][br*72 + bc*8]      = *(const u16x8*)pb;
    // prefetch step 1
    u16x8 ra0 = {}, ra1 = {}, rb = {};
    if (1 < ns) {
        ra0 = *(const u16x8*)(pa + 64);
        ra1 = *(const u16x8*)(pa + 96);
        rb  = *(const u16x8*)(pb + 64);
    }

    f32x4 acc[2][2] = {};
    for (int s = 0; s < ns; ++s) {
        __syncthreads();                 // buf[s&1] ready; compute(s-1) done
        const int cb = s & 1, nb = cb ^ 1;
        if (s + 1 < ns) {
            *(u16x8*)&As[nb][ar*72 + ac*8]      = ra0;
            *(u16x8*)&As[nb][ar*72 + 32 + ac*8] = ra1;
            *(u16x8*)&Bs[nb][br*72 + bc*8]      = rb;
            if (s + 2 < ns) {
                ra0 = *(const u16x8*)(pa + 64*(s+2));
                ra1 = *(const u16x8*)(pa + 64*(s+2) + 32);
                rb  = *(const u16x8*)(pb + 64*(s+2));
            }
        }
        #pragma unroll
        for (int c = 0; c < 2; ++c) {
            bf16x8 a0 = *(const bf16x8*)&As[cb][(mp*32      + fr)*72 + c*32 + fg*8];
            bf16x8 a1 = *(const bf16x8*)&As[cb][(mp*32 + 16 + fr)*72 + c*32 + fg*8];
            #pragma unroll
            for (int t = 0; t < 2; ++t) {
                bf16x8 b = *(const bf16x8*)&Bs[cb][((np*2+t)*16 + fr)*72 + c*32 + fg*8];
                acc[0][t] = __builtin_amdgcn_mfma_f32_16x16x32_bf16(a0, b, acc[0][t], 0, 0, 0);
                acc[1][t] = __builtin_amdgcn_mfma_f32_16x16x32_bf16(a1, b, acc[1][t], 0, 0, 0);
            }
        }
    }
    #pragma unroll
    for (int at = 0; at < 2; ++at) {
        #pragma unroll
        for (int t = 0; t < 2; ++t) {
            int gn = n0 + (np*2+t)*16 + fr;
            float bv = bias ? bias[gn] : 0.f;
            #pragma unroll
            for (int i = 0; i < 4; ++i) {
                int gm = m0 + mp*32 + at*16 + fg*4 + i;
                float v = acc[at][t][i] + bv;
                if (res) v += res[(size_t)gm*N + gn];
                if (out) out[(size_t)gm*N + gn] = v;
                if (out_bf) out_bf[(size_t)gm*N + gn] = f2b(v);
            }
        }
    }
}

// --------- QKV GEMM (bf16 A) + merged ctx K/V GEMM, one 1060-block launch.
// blocks 0..959: Q,K -> out_bf[8192][960] (cols 0..639); V (cols 640..959)
// written DIRECTLY TRANSPOSED to vt_self[(b*320+c)*1024 + p].
// blocks 960..1059: ctx K/V. m = bi&63 (XCD locality). BK=32 (occupancy-bound).
__global__ __launch_bounds__(512) void gemm_qkv_ctx(
    const u16* __restrict__ A, const u16* __restrict__ Wt,
    u16* __restrict__ out_bf, u16* __restrict__ vt_self,
    const u16* __restrict__ ctx, const u16* __restrict__ wk,
    const u16* __restrict__ wv, u16* __restrict__ kout, u16* __restrict__ vout)
{
    __shared__ u16 As[2][128*40];
    __shared__ u16 Bs[2][64*40];
    const int tid  = threadIdx.x;
    const int lane = tid & 63;
    const int w    = tid >> 6;
    const int fr   = lane & 15, fg = lane >> 4;
    const int bi   = blockIdx.x;

    if (bi < 960) {
        const int K  = Cch, N = 960;
        const int m0 = (bi & 63)*128;        // m fastest -> same XCD per m
        const int n0 = (bi >> 6)*64;
        const int mp = w >> 1, np = w & 1;
        const int ar = tid >> 2, ac = tid & 3;
        const bool hasB = tid < 256;

        const u16* pa = A  + (size_t)(m0 + ar)*K + ac*8;
        const u16* pb = Wt + (size_t)(n0 + ar)*K + ac*8;
        const int nk = K >> 5;                  // 10

        *(u16x8*)&As[0][ar*40 + ac*8] = *(const u16x8*)pa;
        if (hasB) *(u16x8*)&Bs[0][ar*40 + ac*8] = *(const u16x8*)pb;
        u16x8 xa = *(const u16x8*)(pa + 32);
        u16x8 ya = *(const u16x8*)(pa + 64);
        u16x8 xb = {}, yb = {};
        if (hasB) { xb = *(const u16x8*)(pb + 32); yb = *(const u16x8*)(pb + 64); }

        f32x4 acc[2][2] = {};
        for (int i = 0; i < nk; i += 2) {
            __syncthreads();
            *(u16x8*)&As[1][ar*40 + ac*8] = xa;
            if (hasB) *(u16x8*)&Bs[1][ar*40 + ac*8] = xb;
            if (i + 3 < nk) {
                xa = *(const u16x8*)(pa + 32*(i+3));
                if (hasB) xb = *(const u16x8*)(pb + 32*(i+3));
            }
            {
                bf16x8 a0 = *(const bf16x8*)&As[0][(mp*32      + fr)*40 + fg*8];
                bf16x8 a1 = *(const bf16x8*)&As[0][(mp*32 + 16 + fr)*40 + fg*8];
                #pragma unroll
                for (int t = 0; t < 2; ++t) {
                    bf16x8 b = *(const bf16x8*)&Bs[0][((np*2+t)*16 + fr)*40 + fg*8];
                    acc[0][t] = __builtin_amdgcn_mfma_f32_16x16x32_bf16(a0, b, acc[0][t], 0, 0, 0);
                    acc[1][t] = __builtin_amdgcn_mfma_f32_16x16x32_bf16(a1, b, acc[1][t], 0, 0, 0);
                }
            }
            __syncthreads();
            if (i + 2 < nk) {
                *(u16x8*)&As[0][ar*40 + ac*8] = ya;
                if (hasB) *(u16x8*)&Bs[0][ar*40 + ac*8] = yb;
                if (i + 4 < nk) {
                    ya = *(const u16x8*)(pa + 32*(i+4));
                    if (hasB) yb = *(const u16x8*)(pb + 32*(i+4));
                }
            }
            {
                bf16x8 a0 = *(const bf16x8*)&As[1][(mp*32      + fr)*40 + fg*8];
                bf16x8 a1 = *(const bf16x8*)&As[1][(mp*32 + 16 + fr)*40 + fg*8];
                #pragma unroll
                for (int t = 0; t < 2; ++t) {
                    bf16x8 b = *(const bf16x8*)&Bs[1][((np*2+t)*16 + fr)*40 + fg*8];
                    acc[0][t] = __builtin_amdgcn_mfma_f32_16x16x32_bf16(a0, b, acc[0][t], 0, 0, 0);
                    acc[1][t] = __builtin_amdgcn_mfma_f32_16x16x32_bf16(a1, b, acc[1][t], 0, 0, 0);
                }
            }
        }
        if (n0 < 640) {                       // Q,K: token-major
            #pragma unroll
            for (int at = 0; at < 2; ++at) {
                #pragma unroll
                for (int t = 0; t < 2; ++t) {
                    int gn = n0 + (np*2+t)*16 + fr;
                    #pragma unroll
                    for (int i = 0; i < 4; ++i) {
                        int gm = m0 + mp*32 + at*16 + fg*4 + i;
                        out_bf[(size_t)gm*N + gn] = f2b(acc[at][t][i]);
                    }
                }
            }
        } else {                              // V: write V^T directly
            #pragma unroll
            for (int at = 0; at < 2; ++at) {
                #pragma unroll
                for (int t = 0; t < 2; ++t) {
                    int c  = n0 - 640 + (np*2+t)*16 + fr;   // 0..319
                    int gm0 = m0 + mp*32 + at*16 + fg*4;    // multiple of 4
                    int b  = gm0 >> 10;
                    int p  = gm0 & (HW-1);
                    u16x4 vv;
                    #pragma unroll
                    for (int i = 0; i < 4; ++i) vv[i] = f2b(acc[at][t][i]);
                    *(u16x4*)&vt_self[((size_t)(b*Cch + c))*HW + p] = vv;
                }
            }
        }
        return;
    }

    // ---------------- merged ctx K/V path (blocks 960..1059) --------------
    {
        int cb = bi - 960;                   // 0..99
        const int z  = cb / 50; cb -= z*50;
        const int my = cb / 5, nx0 = cb - my*5;
        const int m0 = my*64, n0 = nx0*64;
        const u16* Wt2 = z ? wv : wk;
        u16* outp      = z ? vout : kout;
        const int mg = w >> 1;
        const int np = w & 1;
        const bool isA = tid < 256;
        const int cr = (tid & 255) >> 2, cc = tid & 3;

        const u16* ps = isA ? ctx + (size_t)(m0 + cr)*CTXD + cc*8
                            : Wt2 + (size_t)(n0 + cr)*CTXD + cc*8;
        u16* s0 = isA ? &As[0][cr*40 + cc*8] : &Bs[0][cr*40 + cc*8];
        u16* s1 = isA ? &As[1][cr*40 + cc*8] : &Bs[1][cr*40 + cc*8];
        const int nk = CTXD >> 5;    // 24

        *(u16x8*)s0 = *(const u16x8*)ps;
        u16x8 xv = *(const u16x8*)(ps + 32);
        u16x8 yv = *(const u16x8*)(ps + 64);

        f32x4 acc[2] = {};
        for (int i = 0; i < nk; i += 2) {
            __syncthreads();
            *(u16x8*)s1 = xv;
            if (i + 3 < nk) xv = *(const u16x8*)(ps + 32*(i+3));
            {
                bf16x8 a = *(const bf16x8*)&As[0][(mg*16 + fr)*40 + fg*8];
                #pragma unroll
                for (int t = 0; t < 2; ++t) {
                    bf16x8 b = *(const bf16x8*)&Bs[0][((np*2+t)*16 + fr)*40 + fg*8];
                    acc[t] = __builtin_amdgcn_mfma_f32_16x16x32_bf16(a, b, acc[t], 0, 0, 0);
                }
            }
            __syncthreads();
            if (i + 2 < nk) {
                *(u16x8*)s0 = yv;
                if (i + 4 < nk) yv = *(const u16x8*)(ps + 32*(i+4));
            }
            {
                bf16x8 a = *(const bf16x8*)&As[1][(mg*16 + fr)*40 + fg*8];
                #pragma unroll
                for (int t = 0; t < 2; ++t) {
                    bf16x8 b = *(const bf16x8*)&Bs[1][((np*2+t)*16 + fr)*40 + fg*8];
                    acc[t] = __builtin_amdgcn_mfma_f32_16x16x32_bf16(a, b, acc[t], 0, 0, 0);
                }
            }
        }
        #pragma unroll
        for (int t = 0; t < 2; ++t) {
            int gn = n0 + (np*2+t)*16 + fr;
            #pragma unroll
            for (int i = 0; i < 4; ++i) {
                int gm = m0 + mg*16 + fg*4 + i;
                if (gm < MCTX)
                    outp[(size_t)gm*Cch + gn] = f2b(acc[t][i]);
            }
        }
    }
}

// ---- proj_out GEMM + transpose + residual, BK=64 depth-2 loop (ns=5)
__global__ __launch_bounds__(512) void gemm_pout(
    const u16* __restrict__ A, const u16* __restrict__ Wt,
    const float* __restrict__ bias, const float* __restrict__ x,
    float* __restrict__ out, int K)
{
    __shared__ u16 As[2][128*72];
    __shared__ u16 Bs[2][64*72];
    const int tid  = threadIdx.x;
    const int lane = tid & 63;
    const int w    = tid >> 6;
    const int mp   = w >> 1;
    const int np   = w & 1;
    const int m0   = blockIdx.x * 128;
    const int n0   = blockIdx.y * 64;
    const int fr   = lane & 15, fg = lane >> 4;
    const int ar   = tid >> 2, ac = tid & 3;
    const int br   = tid >> 3, bc = tid & 7;

    const u16* pa = A  + (size_t)(m0 + ar)*K + ac*8;
    const u16* pb = Wt + (size_t)(n0 + br)*K + bc*8;
    const int ns = K >> 6;                      // 5

    *(u16x8*)&As[0][ar*72 + ac*8]      = *(const u16x8*)pa;
    *(u16x8*)&As[0][ar*72 + 32 + ac*8] = *(const u16x8*)(pa + 32);
    *(u16x8*)&Bs[0][br*72 + bc*8]      = *(const u16x8*)pb;
    u16x8 ra0 = {}, ra1 = {}, rb = {};
    if (1 < ns) {
        ra0 = *(const u16x8*)(pa + 64);
        ra1 = *(const u16x8*)(pa + 96);
        rb  = *(const u16x8*)(pb + 64);
    }

    f32x4 acc[2][2] = {};
    for (int s = 0; s < ns; ++s) {
        __syncthreads();
        const int cb = s & 1, nb = cb ^ 1;
        if (s + 1 < ns) {
            *(u16x8*)&As[nb][ar*72 + ac*8]      = ra0;
            *(u16x8*)&As[nb][ar*72 + 32 + ac*8] = ra1;
            *(u16x8*)&Bs[nb][br*72 + bc*8]      = rb;
            if (s + 2 < ns) {
                ra0 = *(const u16x8*)(pa + 64*(s+2));
                ra1 = *(const u16x8*)(pa + 64*(s+2) + 32);
                rb  = *(const u16x8*)(pb + 64*(s+2));
            }
        }
        #pragma unroll
        for (int c = 0; c < 2; ++c) {
            bf16x8 a0 = *(const bf16x8*)&As[cb][(mp*32      + fr)*72 + c*32 + fg*8];
            bf16x8 a1 = *(const bf16x8*)&As[cb][(mp*32 + 16 + fr)*72 + c*32 + fg*8];
            #pragma unroll
            for (int t = 0; t < 2; ++t) {
                bf16x8 b = *(const bf16x8*)&Bs[cb][((np*2+t)*16 + fr)*72 + c*32 + fg*8];
                acc[0][t] = __builtin_amdgcn_mfma_f32_16x16x32_bf16(a0, b, acc[0][t], 0, 0, 0);
                acc[1][t] = __builtin_amdgcn_mfma_f32_16x16x32_bf16(a1, b, acc[1][t], 0, 0, 0);
            }
        }
    }
    #pragma unroll
    for (int at = 0; at < 2; ++at) {
        #pragma unroll
        for (int t = 0; t < 2; ++t) {
            int gn = n0 + (np*2+t)*16 + fr;
            float bv = bias[gn];
            int gm0 = m0 + mp*32 + at*16 + fg*4;     // multiple of 4
            int b   = gm0 >> 10;
            int pcol= gm0 & (HW-1);
            size_t o = ((size_t)(b*Cch + gn))*HW + pcol;
            f32x4 xv = *(const f32x4*)&x[o];
            f32x4 vv;
            #pragma unroll
            for (int i = 0; i < 4; ++i) vv[i] = acc[at][t][i] + bv + xv[i];
            *(f32x4*)&out[o] = vv;
        }
    }
}

// ---- GEGLU fused MFMA GEMM. 512 threads / 8 waves, each wave 32x32 with
// both a- and g-accumulators (8 MFMA/chunk). Grid (m,n): m fastest. BK=32.
__global__ __launch_bounds__(512) void geglu_bf16(
    const u16* __restrict__ A, const u16* __restrict__ Wt,
    const float* __restrict__ b1, u16* __restrict__ out, int M, int K)
{
    __shared__ u16 As[2][128*40];
    __shared__ u16 Ba[2][64*40];
    __shared__ u16 Bg[2][64*40];
    const int tid  = threadIdx.x;
    const int lane = tid & 63;
    const int w    = tid >> 6;
    const int mp   = w >> 1;            // 0..3
    const int np   = w & 1;
    const int m0   = blockIdx.x * 128;   // m fastest (XCD locality)
    const int n0   = blockIdx.y * 64;
    const int fr   = lane & 15, fg = lane >> 4;
    const int ar   = tid >> 2, ac = tid & 3;     // 0..127 rows, 4 chunks
    const int nk   = K >> 5;   // 10

    const u16* pa = A + (size_t)(m0 + ar)*K + ac*8;
    // B rows 0..63 -> Ba, 64..127 -> Bg (at Wt row FFI + n0 + ..)
    const int bq = (ar < 64) ? (n0 + ar) : (FFI + n0 + ar - 64);
    const u16* pb = Wt + (size_t)bq*K + ac*8;
    u16* bs0 = (ar < 64) ? &Ba[0][ar*40 + ac*8] : &Bg[0][(ar-64)*40 + ac*8];
    u16* bs1 = (ar < 64) ? &Ba[1][ar*40 + ac*8] : &Bg[1][(ar-64)*40 + ac*8];

    *(u16x8*)&As[0][ar*40 + ac*8] = *(const u16x8*)pa;
    *(u16x8*)bs0 = *(const u16x8*)pb;
    u16x8 xa = *(const u16x8*)(pa + 32);
    u16x8 xb = *(const u16x8*)(pb + 32);
    u16x8 ya = *(const u16x8*)(pa + 64);
    u16x8 yb = *(const u16x8*)(pb + 64);

    f32x4 aca[2][2] = {}, acg[2][2] = {};
    for (int i = 0; i < nk; i += 2) {
        __syncthreads();
        *(u16x8*)&As[1][ar*40 + ac*8] = xa;
        *(u16x8*)bs1 = xb;
        if (i + 3 < nk) {
            xa = *(const u16x8*)(pa + 32*(i+3));
            xb = *(const u16x8*)(pb + 32*(i+3));
        }
        {
            bf16x8 a0 = *(const bf16x8*)&As[0][(mp*32      + fr)*40 + fg*8];
            bf16x8 a1 = *(const bf16x8*)&As[0][(mp*32 + 16 + fr)*40 + fg*8];
            #pragma unroll
            for (int t = 0; t < 2; ++t) {
                bf16x8 ba = *(const bf16x8*)&Ba[0][((np*2+t)*16 + fr)*40 + fg*8];
                bf16x8 bg = *(const bf16x8*)&Bg[0][((np*2+t)*16 + fr)*40 + fg*8];
                aca[0][t] = __builtin_amdgcn_mfma_f32_16x16x32_bf16(a0, ba, aca[0][t], 0, 0, 0);
                aca[1][t] = __builtin_amdgcn_mfma_f32_16x16x32_bf16(a1, ba, aca[1][t], 0, 0, 0);
                acg[0][t] = __builtin_amdgcn_mfma_f32_16x16x32_bf16(a0, bg, acg[0][t], 0, 0, 0);
                acg[1][t] = __builtin_amdgcn_mfma_f32_16x16x32_bf16(a1, bg, acg[1][t], 0, 0, 0);
            }
        }
        __syncthreads();
        if (i + 2 < nk) {
            *(u16x8*)&As[0][ar*40 + ac*8] = ya;
            *(u16x8*)bs0 = yb;
            if (i + 4 < nk) {
                ya = *(const u16x8*)(pa + 32*(i+4));
                yb = *(const u16x8*)(pb + 32*(i+4));
            }
        }
        {
            bf16x8 a0 = *(const bf16x8*)&As[1][(mp*32      + fr)*40 + fg*8];
            bf16x8 a1 = *(const bf16x8*)&As[1][(mp*32 + 16 + fr)*40 + fg*8];
            #pragma unroll
            for (int t = 0; t < 2; ++t) {
                bf16x8 ba = *(const bf16x8*)&Ba[1][((np*2+t)*16 + fr)*40 + fg*8];
                bf16x8 bg = *(const bf16x8*)&Bg[1][((np*2+t)*16 + fr)*40 + fg*8];
                aca[0][t] = __builtin_amdgcn_mfma_f32_16x16x32_bf16(a0, ba, aca[0][t], 0, 0, 0);
                aca[1][t] = __builtin_amdgcn_mfma_f32_16x16x32_bf16(a1, ba, aca[1][t], 0, 0, 0);
                acg[0][t] = __builtin_amdgcn_mfma_f32_16x16x32_bf16(a0, bg, acg[0][t], 0, 0, 0);
                acg[1][t] = __builtin_amdgcn_mfma_f32_16x16x32_bf16(a1, bg, acg[1][t], 0, 0, 0);
            }
        }
    }
    #pragma unroll
    for (int at = 0; at < 2; ++at) {
        #pragma unroll
        for (int t = 0; t < 2; ++t) {
            int gn = n0 + (np*2+t)*16 + fr;
            float ba = b1[gn], bg = b1[FFI + gn];
            #pragma unroll
            for (int i = 0; i < 4; ++i) {
                int gm = m0 + mp*32 + at*16 + fg*4 + i;
                float av = aca[at][t][i] + ba;
                float gv = acg[at][t][i] + bg;
                float gel = 0.5f*gv*(1.f + erff(gv*0.70710678118654752f));
                out[(size_t)gm*FFI + gn] = f2b(av*gel);
            }
        }
    }
}

// ------------------------------------------------------- MFMA flash attention
// 512 threads / 8 waves, 128-query tiles, double-buffered K/V LDS
// (1 barrier per KV tile), register prefetch, XCD-aware 1-D block decode.
// Q weights pre-scaled by 1/sqrt(40)*log2(e): P = exp2(S) == exp(S_orig).
// Blocks 0..511: attention; blocks 512+: cross-V transpose tail.
__global__ __launch_bounds__(512) void flash_mfma(
    const u16* __restrict__ qb, int qstride,
    const u16* __restrict__ kb, int kstride,
    const u16* __restrict__ vt, int vstride,
    const u64* __restrict__ mbits, int nw,
    u16* __restrict__ out,        // [B*HW][320]
    int Lkv,
    const u16* __restrict__ tin, u16* __restrict__ tout)
{
    __shared__ u16 QPs[128*72];   // Q (stride 72) then P (stride 68), per-wave rows
    __shared__ u16 Ks[2][64*72];
    __shared__ u16 Vs[2][48*72];  // [d][key], row 40 = ones, 41..47 zero

    const int tid  = threadIdx.x;
    const int bi   = blockIdx.x;

    if (bi >= 512) {                        // cross-V transpose tail blocks
        int cb = bi - 512;                  // 0..79
        const int c0 = (cb % 5)*64;
        const int t0 = ((cb/5) & 1)*64;
        const int b  = cb/10;
        {   // stage 64x64 tile, XOR-swizzled 16B chunks (reuse QPs)
            int r = tid >> 3, ch2 = tid & 7;   // 512 threads = 64 rows x 8 chunks
            u16x8 val = {};
            if (t0 + r < CTXL)
                val = *(const u16x8*)(tin + ((size_t)(b*CTXL + t0 + r))*Cch + c0 + ch2*8);
            *(u16x8*)&QPs[r*72 + (ch2 ^ (r & 7))*8] = val;
        }
        __syncthreads();
        for (int e = tid; e < 4096; e += 512) {
            int c = e >> 6, t = e & 63;
            u16 v = QPs[t*72 + (((c >> 3) ^ (t & 7))*8) + (c & 7)];
            tout[((size_t)(b*Cch + c0 + c))*128 + t0 + t] = v;
        }
        return;
    }

    const int lane = tid & 63;
    const int w    = tid >> 6;            // 0..7
    const int col  = lane & 15;
    const int quad = lane >> 4;
    const int hb   = (bi & 7)*8 + (bi >> 6);  // 0..63
    const int qt   = (bi >> 3) & 7;
    const int h    = hb & 7;
    const int b    = hb >> 3;                 // == bi&7
    const int q0   = qt*128;
    const int ch   = tid & 7;
    const int r0   = tid >> 3;            // 0..63

    // stage Q tile rows r0, r0+64 (zero-padded d 40..63), stride 72
    {
        const u16* qT = qb + ((size_t)(b*HW + q0))*qstride + (size_t)h*DHEAD + ch*8;
        u16x8 v0 = {}, v1 = {};
        if (ch < 5) {
            v0 = *(const u16x8*)(qT + (size_t)r0*qstride);
            v1 = *(const u16x8*)(qT + (size_t)(r0+64)*qstride);
        }
        *(u16x8*)&QPs[r0*72 + ch*8]      = v0;
        *(u16x8*)&QPs[(r0+64)*72 + ch*8] = v1;
    }
    // constant V rows 40..47 in BOTH buffers (row 40 = ones)
    if (tid < 128) {
        int rr  = tid >> 3;               // 0..15
        int row = 40 + (rr & 7);
        int buf = rr >> 3;
        u16x8 v = {};
        if (row == DHEAD) {
            #pragma unroll
            for (int z = 0; z < 8; ++z) v[z] = 0x3F80;   // bf16 1.0
        }
        *(u16x8*)&Vs[buf][row*72 + ch*8] = v;
    }

    // incremental row pointers (bumped by 64 keys per tile)
    const bool kok = ch < 5;
    const u16* kR = kb + (size_t)b*Lkv*kstride + (size_t)h*DHEAD + ch*8
                       + (size_t)r0*kstride;
    const u16* vR = vt + ((size_t)(b*Cch + h*DHEAD))*vstride + ch*8
                       + (size_t)r0*vstride;
    const bool vok = r0 < DHEAD;
    const u64* mrow = mbits + ((size_t)(b*HW + q0 + w*16 + quad*4))*nw;

    // register-prefetch tile 0
    u16x8 nk = {}, nv = {};
    if (kok && r0 < Lkv) nk = *(const u16x8*)kR;
    if (vok) nv = *(const u16x8*)vR;

    __syncthreads();
    const bf16x8 qa0 = *(const bf16x8*)&QPs[(w*16 + col)*72 +  0 + quad*8];
    const bf16x8 qa1 = *(const bf16x8*)&QPs[(w*16 + col)*72 + 32 + quad*8];

    f32x4 acc_o[3] = {};

    const int nkt = (Lkv + 63) / 64;
    int cur = 0;
    for (int jt = 0; jt < nkt; ++jt) {
        // write prefetched tile -> buf[cur]
        *(u16x8*)&Ks[cur][r0*72 + ch*8] = nk;
        if (vok) *(u16x8*)&Vs[cur][r0*72 + ch*8] = nv;
        if (jt + 1 < nkt) {                // prefetch next tile (overlaps compute)
            kR += (size_t)64*kstride;
            vR += 64;
            nk = (u16x8){};
            if (kok && ((jt+1)*64 + r0 < Lkv)) nk = *(const u16x8*)kR;
            if (vok) nv = *(const u16x8*)vR;
        }
        __syncthreads();

        // mask words (latency overlaps MFMA below)
        u64 mw[4];
        #pragma unroll
        for (int i = 0; i < 4; ++i) mw[i] = mrow[i*nw + jt];

        // S = Q K^T (prescaled, log2 domain)
        f32x4 s[4] = {};
        #pragma unroll
        for (int nt = 0; nt < 4; ++nt) {
            bf16x8 b0 = *(const bf16x8*)&Ks[cur][(nt*16 + col)*72 +  0 + quad*8];
            bf16x8 b1 = *(const bf16x8*)&Ks[cur][(nt*16 + col)*72 + 32 + quad*8];
            s[nt] = __builtin_amdgcn_mfma_f32_16x16x32_bf16(qa0, b0, s[nt], 0, 0, 0);
            s[nt] = __builtin_amdgcn_mfma_f32_16x16x32_bf16(qa1, b1, s[nt], 0, 0, 0);
        }

        // P = exp2(S) (no shift), zero masked keys
        #pragma unroll
        for (int i = 0; i < 4; ++i) {
            #pragma unroll
            for (int nt = 0; nt < 4; ++nt) {
                float p = __builtin_amdgcn_exp2f(s[nt][i]);
                unsigned bits = (unsigned)(mw[i] >> (nt*16));
                s[nt][i] = ((bits >> col) & 1u) ? p : 0.f;
            }
        }

        // P -> LDS, stride 68 (per-wave rows, no cross-wave sharing)
        #pragma unroll
        for (int nt = 0; nt < 4; ++nt)
            #pragma unroll
            for (int i = 0; i < 4; ++i)
                QPs[(w*16 + quad*4 + i)*68 + nt*16 + col] =
                    (u16)(__float_as_uint(s[nt][i]) >> 16);

        // O += P V   (col 40 accumulates l)
        bf16x8 pa0, pa1;
        __builtin_memcpy(&pa0, &QPs[(w*16 + col)*68 +  0 + quad*8], 16);
        __builtin_memcpy(&pa1, &QPs[(w*16 + col)*68 + 32 + quad*8], 16);
        #pragma unroll
        for (int nt = 0; nt < 3; ++nt) {
            bf16x8 vb0 = *(const bf16x8*)&Vs[cur][(nt*16 + col)*72 +  0 + quad*8];
            bf16x8 vb1 = *(const bf16x8*)&Vs[cur][(nt*16 + col)*72 + 32 + quad*8];
            acc_o[nt] = __builtin_amdgcn_mfma_f32_16x16x32_bf16(pa0, vb0, acc_o[nt], 0, 0, 0);
            acc_o[nt] = __builtin_amdgcn_mfma_f32_16x16x32_bf16(pa1, vb1, acc_o[nt], 0, 0, 0);
        }
        cur ^= 1;
    }

    // l_i lives in acc_o[2] at col 40 (lane col==8 of each 16-group)
    float inv_l[4];
    #pragma unroll
    for (int i = 0; i < 4; ++i)
        inv_l[i] = 1.f / __shfl(acc_o[2][i], (lane & 48) | 8);

    #pragma unroll
    for (int nt = 0; nt < 3; ++nt) {
        int d = nt*16 + col;
        if (d < DHEAD) {
            #pragma unroll
            for (int i = 0; i < 4; ++i) {
                int q = q0 + w*16 + quad*4 + i;
                out[((size_t)(b*HW + q))*Cch + h*DHEAD + d] = f2b(acc_o[nt][i] * inv_l[i]);
            }
        }
    }
}

// ---------------------------------------------------------------------------
extern "C" void kernel_launch(void* const* d_in, const int* in_sizes, int n_in,
                              void* d_out, int out_size, void* d_ws, size_t ws_size,
                              hipStream_t stream)
{
    const float* x        = (const float*)d_in[0];
    const float* context  = (const float*)d_in[1];
    const void*  vis_mask = d_in[2];
    const void*  v2t_mask = d_in[3];
    const float* gn_s     = (const float*)d_in[4];
    const float* gn_b     = (const float*)d_in[5];
    const float* proj_in_w= (const float*)d_in[6];
    const float* proj_in_b= (const float*)d_in[7];
    const float* n1_s     = (const float*)d_in[8];
    const float* n1_b     = (const float*)d_in[9];
    const float* wq1      = (const float*)d_in[10];
    const float* wk1      = (const float*)d_in[11];
    const float* wv1      = (const float*)d_in[12];
    const float* wo1      = (const float*)d_in[13];
    const float* bo1      = (const float*)d_in[14];
    const float* n2_s     = (const float*)d_in[15];
    const float* n2_b     = (const float*)d_in[16];
    const float* wq2      = (const float*)d_in[17];
    const float* wk2      = (const float*)d_in[18];
    const float* wv2      = (const float*)d_in[19];
    const float* wo2      = (const float*)d_in[20];
    const float* bo2      = (const float*)d_in[21];
    const float* n3_s     = (const float*)d_in[22];
    const float* n3_b     = (const float*)d_in[23];
    const float* ff_w1    = (const float*)d_in[24];
    const float* ff_b1    = (const float*)d_in[25];
    const float* ff_w2    = (const float*)d_in[26];
    const float* ff_b2    = (const float*)d_in[27];
    const float* pout_w   = (const float*)d_in[28];
    const float* pout_b   = (const float*)d_in[29];
    float* out = (float*)d_out;

    const size_t TOKC = (size_t)NTOK*Cch;        // 2,621,440
    float* ws   = (float*)d_ws;
    float* Hb   = ws;                            // fp32 residual spine
    u16*   QKV  = (u16*)(Hb + TOKC);             // [8192][960] packed, 3*TOKC
    u16*   Vt_g = QKV + 3*TOKC;                  // self V^T, TOKC
    u16*   G_bf = QKV;                           // FF reuse (4*TOKC)
    u16*   T0b  = Vt_g + TOKC;                   // GN/LN out, TOKC
    u16*   T1b  = T0b + TOKC;                    // attn out, TOKC
    u16*   Hb_bf= T1b + TOKC;                    // bf16 mirror post-FF, TOKC
    u16*   Wbf  = Hb_bf + TOKC;                  // 2,539,520 u16
    u64*   mb_vis = (u64*)(Wbf + 2539520);       // 8192*16 u64
    u64*   mb_v2t = mb_vis + 131072;             // 8192*2  u64
    u16*   ctx_bf = (u16*)(mb_v2t + 16384);      // 640*768 u16
    u16*   Kc_bf  = ctx_bf + MCTXP*CTXD;         // ctx K, 616*320 (pad 640)
    u16*   Vc_bf  = Kc_bf + 640*Cch;             // ctx V
    float* gnA    = (float*)(Vc_bf + 640*Cch);   // 8*320 floats
    float* gnB    = gnA + Bsz*Cch;
    u16*   Vt_x   = (u16*)(gnB + Bsz*Cch);       // cross V^T, 8*320*128 u16

    u16* w_q1  = Wbf;                            // q1|k1|v1 contiguous [960][320]
    u16* w_k1  = Wbf +  102400;
    u16* w_v1  = Wbf +  204800;
    u16* w_pin = Wbf +  307200;
    u16* w_o1  = Wbf +  409600;
    u16* w_q2  = Wbf +  512000;
    u16* w_o2  = Wbf +  614400;
    u16* w_ff1 = Wbf +  716800;
    u16* w_ff2 = Wbf + 1536000;
    u16* w_po  = Wbf + 1945600;
    u16* w_k2  = Wbf + 2048000;                  // [320][768]
    u16* w_v2  = Wbf + 2293760;

    // Q scale folds softmax 1/sqrt(40) AND log2(e) so flash uses exp2 directly
    const float qscale = 0.15811388300841897f * 1.4426950408889634f;
    WPack pack;
    pack.w[0]  = { wq1,       w_q1,  Cch, Cch, 25,  qscale };
    pack.w[1]  = { wk1,       w_k1,  Cch, Cch, 25,  1.f };
    pack.w[2]  = { wv1,       w_v1,  Cch, Cch, 25,  1.f };
    pack.w[3]  = { proj_in_w, w_pin, Cch, Cch, 25,  1.f };
    pack.w[4]  = { wo1,       w_o1,  Cch, Cch, 25,  1.f };
    pack.w[5]  = { wq2,       w_q2,  Cch, Cch, 25,  qscale };
    pack.w[6]  = { wo2,       w_o2,  Cch, Cch, 25,  1.f };
    pack.w[7]  = { ff_w1,     w_ff1, Cch, 2*FFI, 200, 1.f };
    pack.w[8]  = { ff_w2,     w_ff2, FFI, Cch, 100, 1.f };
    pack.w[9]  = { pout_w,    w_po,  Cch, Cch, 25,  1.f };
    pack.w[10] = { wk2,       w_k2,  CTXD, Cch, 60, 1.f };
    pack.w[11] = { wv2,       w_v2,  CTXD, Cch, 60, 1.f };
    // total tiles = 7*25 + 200 + 100 + 25 + 60 + 60 = 620 = WT_TILES

    dim3 blk256(256);
    dim3 blk512(512);
    dim3 gTok(NTOK/128, Cch/64);                 // (64,5)  m fastest
    dim3 gFF(NTOK/128, FFI/64);                  // (64,20) m fastest
    dim3 gGN(Cch/64, HW/64, Bsz);                // (5,16,8)

    // fused preamble: weight tiles | ctx | mask-bits(vis,v2t) | gn stats
    preamble<<<WT_TILES + CTXBLK + 4096 + 256, blk256, 0, stream>>>(
        pack, context, ctx_bf, vis_mask, v2t_mask, mb_vis, mb_v2t,
        x, gn_s, gn_b, gnA, gnB);

    gn_apply<<<gGN, blk256, 0, stream>>>(x, gnA, gnB, T0b);
    gemm_bf16<<<gTok, blk512, 0, stream>>>(T0b, w_pin, proj_in_b, nullptr, Hb, nullptr, NTOK, Cch, Cch);

    // --- self attention (QKV + ctx K/V in one launch; V^T written directly) ---
    layernorm_kernel<<<NTOK/4, blk256, 0, stream>>>(Hb, n1_s, n1_b, T0b);
    gemm_qkv_ctx<<<1060, blk512, 0, stream>>>(T0b, w_q1, QKV, Vt_g,
                                              ctx_bf, w_k2, w_v2, Kc_bf, Vc_bf);
    flash_mfma<<<512 + 80, blk512, 0, stream>>>(QKV, 960, QKV + 320, 960, Vt_g, HW,
                                                mb_vis, 16, T1b, HW, Vc_bf, Vt_x);
    gemm_bf16<<<gTok, blk512, 0, stream>>>(T1b, w_o1, bo1, Hb, Hb, nullptr, NTOK, Cch, Cch);

    // --- cross attention ---
    layernorm_kernel<<<NTOK/4, blk256, 0, stream>>>(Hb, n2_s, n2_b, T0b);
    gemm_bf16<<<gTok, blk512, 0, stream>>>(T0b, w_q2, nullptr, nullptr, nullptr, QKV, NTOK, Cch, Cch);
    flash_mfma<<<512, blk512, 0, stream>>>(QKV, Cch, Kc_bf, Cch, Vt_x, 128,
                                           mb_v2t, 2, T1b, CTXL, nullptr, nullptr);
    gemm_bf16<<<gTok, blk512, 0, stream>>>(T1b, w_o2, bo2, Hb, Hb, nullptr, NTOK, Cch, Cch);

    // --- GEGLU feed-forward ---
    layernorm_kernel<<<NTOK/4, blk256, 0, stream>>>(Hb, n3_s, n3_b, T0b);
    geglu_bf16<<<gFF, blk512, 0, stream>>>(T0b, w_ff1, ff_b1, G_bf, NTOK, Cch);
    gemm_bf16<<<gTok, blk512, 0, stream>>>(G_bf, w_ff2, ff_b2, Hb, nullptr, Hb_bf, NTOK, Cch, FFI);

    // --- proj_out + transpose + residual (fused) ---
    gemm_pout<<<gTok, blk512, 0, stream>>>(Hb_bf, w_po, pout_b, x, out, Cch);
}